// Round 9
// baseline (152.928 us; speedup 1.0000x reference)
//
#include <hip/hip_runtime.h>
#include <math.h>

#define B_    4
#define S_    2048
#define IN_   256
#define H_    128
#define M_    128
#define NROWS (B_ * S_)     // 8192
#define RPB   16
#define TPB   256
#define XPAD  260

typedef float f4_t __attribute__((ext_vector_type(4)));

// ---------------- Kernel 1: projections + h,n + k,v,i,f spill ----------------
// GEMM mapping: thread t -> colgroup c=t&31 (cols 4c..4c+3), mat=(t>>5)&3
// (0=q,1=k,2=v,3=o), half=t>>7 (k in [128*half, 128*half+128)).
// Weight loads are float4 (128/thread vs 1024 scalar before); x is full-wave
// broadcast b128 from LDS. Halves combined through qs/ks/vs/os_ LDS arrays.
__global__ __launch_bounds__(TPB) void xlstm_proj(
    const float* __restrict__ x,
    const float* __restrict__ c0,
    const float* __restrict__ n0,
    const float* __restrict__ w_q, const float* __restrict__ b_q,
    const float* __restrict__ w_k, const float* __restrict__ b_k,
    const float* __restrict__ w_v, const float* __restrict__ b_v,
    const float* __restrict__ w_i, const float* __restrict__ b_i,
    const float* __restrict__ w_f, const float* __restrict__ b_f,
    const float* __restrict__ w_o, const float* __restrict__ b_o,
    float* __restrict__ out_h,
    float* __restrict__ out_n,
    float* __restrict__ kws,
    float* __restrict__ vws,
    float* __restrict__ ifws)
{
    __shared__ float xs[RPB][XPAD];     // 16.6 KB
    __shared__ float qs[RPB][M_];       // 8 KB x 4 = 32 KB
    __shared__ float ks[RPB][M_];
    __shared__ float vs[RPB][M_];
    __shared__ float os_[RPB][M_];
    __shared__ float itf[RPB][2];
    __shared__ float scal[RPB][2];

    const int t    = threadIdx.x;
    const int row0 = blockIdx.x * RPB;

    for (int p4 = t; p4 < RPB * IN_ / 4; p4 += TPB) {
        int p = p4 * 4;
        float4 v = *(const float4*)(x + (size_t)row0 * IN_ + p);
        int r = p >> 8, c = p & 255;
        *(float4*)&xs[r][c] = v;
    }
    __syncthreads();

    // ---- main GEMM: 4 cols x 16 rows x 1 matrix x half-k per thread ----
    const int cg   = t & 31;            // col group: cols 4cg..4cg+3
    const int mat  = (t >> 5) & 3;      // 0=q 1=k 2=v 3=o
    const int half = t >> 7;
    const int c4   = cg * 4;

    const float* W = (mat == 0) ? w_q : (mat == 1) ? w_k : (mat == 2) ? w_v : w_o;
    float (*DST)[M_] = (mat == 0) ? qs : (mat == 1) ? ks : (mat == 2) ? vs : os_;

    f4_t acc[16];
    #pragma unroll
    for (int r = 0; r < 16; ++r) acc[r] = (f4_t){0.f, 0.f, 0.f, 0.f};

    const int k0base = half * 128;
    #pragma unroll 2
    for (int it = 0; it < 32; ++it) {
        const int k0 = k0base + it * 4;
        const float* wp = W + (size_t)k0 * H_ + c4;
        f4_t w0 = *(const f4_t*)(wp);
        f4_t w1 = *(const f4_t*)(wp + H_);
        f4_t w2 = *(const f4_t*)(wp + 2 * H_);
        f4_t w3 = *(const f4_t*)(wp + 3 * H_);

        #pragma unroll
        for (int r = 0; r < 16; ++r) {
            f4_t xv = *(const f4_t*)&xs[r][k0];      // full-wave broadcast
            acc[r] += xv.x * w0 + xv.y * w1 + xv.z * w2 + xv.w * w3;
        }
    }

    // combine halves through the destination arrays
    if (half == 1) {
        #pragma unroll
        for (int r = 0; r < 16; ++r)
            *(f4_t*)&DST[r][c4] = acc[r];
    }
    __syncthreads();
    if (half == 0) {
        const float kscale = 0.08838834764831843f;   // 1/sqrt(128)
        const float* BIAS = (mat == 0) ? b_q : (mat == 1) ? b_k : (mat == 2) ? b_v : b_o;
        f4_t b4 = *(const f4_t*)(BIAS + c4);
        #pragma unroll
        for (int r = 0; r < 16; ++r) {
            f4_t s = acc[r] + *(const f4_t*)&DST[r][c4] + b4;
            if (mat == 1) s *= kscale;
            if (mat == 3) {
                s.x = 1.f / (1.f + __expf(-s.x));
                s.y = 1.f / (1.f + __expf(-s.y));
                s.z = 1.f / (1.f + __expf(-s.z));
                s.w = 1.f / (1.f + __expf(-s.w));
            }
            *(f4_t*)&DST[r][c4] = s;
        }
    }

    // ---- gates, wave-parallel (uses only xs) ----
    {
        const int gr = t >> 4, gseg = t & 15;
        const float* xrow = &xs[gr][gseg * 16];
        float pi = 0.f, pf = 0.f;
        #pragma unroll
        for (int u = 0; u < 4; ++u) {
            float4 xv  = *(const float4*)(xrow + u * 4);
            float4 wiv = *(const float4*)(w_i + gseg * 16 + u * 4);
            float4 wfv = *(const float4*)(w_f + gseg * 16 + u * 4);
            pi = fmaf(xv.x, wiv.x, fmaf(xv.y, wiv.y, fmaf(xv.z, wiv.z, fmaf(xv.w, wiv.w, pi))));
            pf = fmaf(xv.x, wfv.x, fmaf(xv.y, wfv.y, fmaf(xv.z, wfv.z, fmaf(xv.w, wfv.w, pf))));
        }
        #pragma unroll
        for (int m = 1; m < 16; m <<= 1) { pi += __shfl_xor(pi, m); pf += __shfl_xor(pf, m); }
        if (gseg == 0) {
            itf[gr][0] = __expf(pi + b_i[0]);
            itf[gr][1] = 1.f / (1.f + __expf(-(pf + b_f[0])));
        }
    }
    __syncthreads();

    // ---- c0q in registers: c0q[r] = sum_j c0[col][j] * q[rbase+r][j] ----
    const int col   = t & 127;
    const int rbase = (t >> 7) * 8;
    float c0qr[8];
    {
        #pragma unroll
        for (int r = 0; r < 8; ++r) c0qr[r] = 0.f;
        const float* c0row = c0 + (size_t)col * M_;
        #pragma unroll 2
        for (int j4 = 0; j4 < M_; j4 += 4) {
            float4 w4 = *(const float4*)(c0row + j4);
            #pragma unroll
            for (int r = 0; r < 8; ++r) {
                float4 q4 = *(const float4*)&qs[rbase + r][j4];
                c0qr[r] = fmaf(w4.x, q4.x, fmaf(w4.y, q4.y, fmaf(w4.z, q4.z, fmaf(w4.w, q4.w, c0qr[r]))));
            }
        }
    }

    // ---- kq, n0q wave-parallel ----
    {
        const int gr = t >> 4, gseg = t & 15;
        const int j0 = gseg * 8;
        float pkq = 0.f, pnq = 0.f;
        #pragma unroll
        for (int u = 0; u < 2; ++u) {
            float4 kk = *(const float4*)&ks[gr][j0 + u * 4];
            float4 qq = *(const float4*)&qs[gr][j0 + u * 4];
            float4 nn = *(const float4*)(n0 + j0 + u * 4);
            pkq = fmaf(kk.x, qq.x, fmaf(kk.y, qq.y, fmaf(kk.z, qq.z, fmaf(kk.w, qq.w, pkq))));
            pnq = fmaf(nn.x, qq.x, fmaf(nn.y, qq.y, fmaf(nn.z, qq.z, fmaf(nn.w, qq.w, pnq))));
        }
        #pragma unroll
        for (int m = 1; m < 16; m <<= 1) { pkq += __shfl_xor(pkq, m); pnq += __shfl_xor(pnq, m); }
        if (gseg == 0) { scal[gr][0] = pkq; scal[gr][1] = pnq; }
    }
    __syncthreads();

    #pragma unroll
    for (int r = 0; r < 8; ++r) {
        int row = rbase + r;
        size_t grow = (size_t)(row0 + row);
        float iv = itf[row][0], fv = itf[row][1];
        float kv = ks[row][col];
        out_n[grow * M_ + col] = fmaf(fv, n0[col], iv * kv);
        float nq    = fmaf(fv, scal[row][1], iv * scal[row][0]);
        float denom = fmaxf(fabsf(nq), 1.0f);
        float ht = fmaf(fv, c0qr[r], iv * vs[row][col] * scal[row][0]) / denom;
        out_h[grow * H_ + col] = os_[row][col] * ht;
        kws[grow * M_ + col] = kv;
        vws[grow * M_ + col] = vs[row][col];
    }
    if (t < 32) {
        int r = t & 15;
        size_t grow = (size_t)(row0 + r);
        if (t < 16) ifws[grow * 2 + 0] = itf[r][0];
        else        ifws[grow * 2 + 1] = itf[r][1];
    }
}

// ---------------- Kernel 2: c stream, 16 rows per block, nt stores ----------------
// (byte-identical to R3's cstream)
__global__ __launch_bounds__(TPB) void xlstm_cstream(
    const float* __restrict__ c0,
    const float* __restrict__ kws,
    const float* __restrict__ vws,
    const float* __restrict__ ifws,
    float* __restrict__ out_c)
{
    const int t    = threadIdx.x;
    const int row0 = blockIdx.x * RPB;

    __shared__ float vsh[RPB][M_];
    __shared__ float ksh[RPB][M_];
    __shared__ float2 ish[RPB];

    for (int p4 = t; p4 < RPB * M_ / 4; p4 += TPB) {
        int idx = p4 * 4;
        int r = idx >> 7, c = idx & 127;
        *(float4*)&vsh[r][c] = *(const float4*)(vws + (size_t)row0 * M_ + idx);
        *(float4*)&ksh[r][c] = *(const float4*)(kws + (size_t)row0 * M_ + idx);
    }
    if (t < RPB) ish[t] = *(const float2*)(ifws + (size_t)(row0 + t) * 2);
    __syncthreads();

    const int base = t * 4;
    const int j    = base & 127;

    #pragma unroll 2
    for (int ch = 0; ch < 16; ++ch) {
        int p = (ch << 10) + base;
        int m = p >> 7;
        float4 c0v = *(const float4*)(c0 + p);
        #pragma unroll
        for (int r = 0; r < RPB; ++r) {
            float4 k4 = *(const float4*)&ksh[r][j];
            float  s  = ish[r].x * vsh[r][m];
            f4_t o4;
            o4.x = fmaf(ish[r].y, c0v.x, s * k4.x);
            o4.y = fmaf(ish[r].y, c0v.y, s * k4.y);
            o4.z = fmaf(ish[r].y, c0v.z, s * k4.z);
            o4.w = fmaf(ish[r].y, c0v.w, s * k4.w);
            __builtin_nontemporal_store(o4,
                (f4_t*)(out_c + (size_t)(row0 + r) * (M_ * M_) + p));
        }
    }
}

extern "C" void kernel_launch(void* const* d_in, const int* in_sizes, int n_in,
                              void* d_out, int out_size, void* d_ws, size_t ws_size,
                              hipStream_t stream) {
    const float* x   = (const float*)d_in[0];
    const float* c0  = (const float*)d_in[1];
    const float* n0  = (const float*)d_in[2];
    const float* w_q = (const float*)d_in[3];  const float* b_q = (const float*)d_in[4];
    const float* w_k = (const float*)d_in[5];  const float* b_k = (const float*)d_in[6];
    const float* w_v = (const float*)d_in[7];  const float* b_v = (const float*)d_in[8];
    const float* w_i = (const float*)d_in[9];  const float* b_i = (const float*)d_in[10];
    const float* w_f = (const float*)d_in[11]; const float* b_f = (const float*)d_in[12];
    const float* w_o = (const float*)d_in[13]; const float* b_o = (const float*)d_in[14];

    float* out   = (float*)d_out;
    float* out_h = out;
    float* out_c = out + (size_t)NROWS * H_;
    float* out_n = out_c + (size_t)NROWS * M_ * M_;

    float* kws  = (float*)d_ws;
    float* vws  = kws + (size_t)NROWS * M_;
    float* ifws = vws + (size_t)NROWS * M_;

    hipLaunchKernelGGL(xlstm_proj, dim3(NROWS / RPB), dim3(TPB), 0, stream,
                       x, c0, n0, w_q, b_q, w_k, b_k, w_v, b_v,
                       w_i, b_i, w_f, b_f, w_o, b_o,
                       out_h, out_n, kws, vws, ifws);

    hipLaunchKernelGGL(xlstm_cstream, dim3(NROWS / RPB), dim3(TPB), 0, stream,
                       c0, kws, vws, ifws, out_c);
}

// Round 10
// 147.690 us; speedup vs baseline: 1.0355x; 1.0355x over previous
//
#include <hip/hip_runtime.h>
#include <math.h>

#define B_    4
#define S_    2048
#define IN_   256
#define H_    128
#define M_    128
#define NROWS (B_ * S_)     // 8192
#define RPB   16            // rows per block
#define GRP   4             // rows per group (4 groups)
#define TPB   256
#define XPAD  260

typedef float f4_t __attribute__((ext_vector_type(4)));

// Fused kernel: per block, 16 rows processed as 4 groups of 4 rows.
// Per group: GEMM (full-k per thread, no combine) -> B -> c0q/scal -> B ->
// h,n writes + c-stream stores (nt, fire-and-forget). The next group's k-loop
// issues right after the stores with no barrier between, so HBM store drain
// overlaps proj VALU work.
__global__ __launch_bounds__(TPB) void xlstm_fused(
    const float* __restrict__ x,
    const float* __restrict__ c0,
    const float* __restrict__ n0,
    const float* __restrict__ w_q, const float* __restrict__ b_q,
    const float* __restrict__ w_k, const float* __restrict__ b_k,
    const float* __restrict__ w_v, const float* __restrict__ b_v,
    const float* __restrict__ w_i, const float* __restrict__ b_i,
    const float* __restrict__ w_f, const float* __restrict__ b_f,
    const float* __restrict__ w_o, const float* __restrict__ b_o,
    float* __restrict__ out_h,
    float* __restrict__ out_c,
    float* __restrict__ out_n)
{
    __shared__ float xs[RPB][XPAD];     // 16.6 KB
    __shared__ float qs[RPB][M_];       // 8 KB x 4
    __shared__ float ks[RPB][M_];
    __shared__ float vs[RPB][M_];
    __shared__ float os_[RPB][M_];
    __shared__ float itf[RPB][2];
    __shared__ float scal[RPB][2];

    const int t    = threadIdx.x;
    const int row0 = blockIdx.x * RPB;

    // ---- stage x (16 rows x 256) ----
    for (int p4 = t; p4 < RPB * IN_ / 4; p4 += TPB) {
        int p = p4 * 4;
        float4 v = *(const float4*)(x + (size_t)row0 * IN_ + p);
        int r = p >> 8, c = p & 255;
        *(float4*)&xs[r][c] = v;
    }
    __syncthreads();

    // ---- gates for all 16 rows (wave-parallel; visible after B of group 0) ----
    {
        const int gr = t >> 4, gseg = t & 15;
        const float* xrow = &xs[gr][gseg * 16];
        float pi = 0.f, pf = 0.f;
        #pragma unroll
        for (int u = 0; u < 4; ++u) {
            float4 xv  = *(const float4*)(xrow + u * 4);
            float4 wiv = *(const float4*)(w_i + gseg * 16 + u * 4);
            float4 wfv = *(const float4*)(w_f + gseg * 16 + u * 4);
            pi = fmaf(xv.x, wiv.x, fmaf(xv.y, wiv.y, fmaf(xv.z, wiv.z, fmaf(xv.w, wiv.w, pi))));
            pf = fmaf(xv.x, wfv.x, fmaf(xv.y, wfv.y, fmaf(xv.z, wfv.z, fmaf(xv.w, wfv.w, pf))));
        }
        #pragma unroll
        for (int m = 1; m < 16; m <<= 1) { pi += __shfl_xor(pi, m); pf += __shfl_xor(pf, m); }
        if (gseg == 0) {
            itf[gr][0] = __expf(pi + b_i[0]);
            itf[gr][1] = 1.f / (1.f + __expf(-(pf + b_f[0])));
        }
    }

    // ---- per-thread GEMM mapping: 4 cols x 1 mat x 2 rows, full k ----
    const int cg  = t & 31;             // col group -> cols 4cg..4cg+3
    const int mat = (t >> 5) & 3;       // 0=q 1=k 2=v 3=o
    const int rh  = t >> 7;             // row half within group
    const int c4  = cg * 4;

    const float* W    = (mat == 0) ? w_q : (mat == 1) ? w_k : (mat == 2) ? w_v : w_o;
    const float* BIAS = (mat == 0) ? b_q : (mat == 1) ? b_k : (mat == 2) ? b_v : b_o;
    float (*DST)[M_]  = (mat == 0) ? qs  : (mat == 1) ? ks  : (mat == 2) ? vs  : os_;
    const f4_t b4 = *(const f4_t*)(BIAS + c4);
    const float kscale = 0.08838834764831843f;   // 1/sqrt(128)

    const int col = t & 127;            // epilogue mapping (same rows as GEMM)

    #pragma unroll 1
    for (int g = 0; g < 4; ++g) {
        const int r0 = g * GRP + rh * 2;          // this thread's 2 rows

        // ---- GEMM: full k = 256, f4 weight loads ----
        f4_t acc0 = (f4_t){0.f,0.f,0.f,0.f};
        f4_t acc1 = (f4_t){0.f,0.f,0.f,0.f};
        #pragma unroll 4
        for (int it = 0; it < 64; ++it) {
            const int k0 = it * 4;
            const float* wp = W + (size_t)k0 * H_ + c4;
            f4_t w0 = *(const f4_t*)(wp);
            f4_t w1 = *(const f4_t*)(wp + H_);
            f4_t w2 = *(const f4_t*)(wp + 2 * H_);
            f4_t w3 = *(const f4_t*)(wp + 3 * H_);
            f4_t xv0 = *(const f4_t*)&xs[r0][k0];        // wave-broadcast
            f4_t xv1 = *(const f4_t*)&xs[r0 + 1][k0];
            acc0 += xv0.x * w0 + xv0.y * w1 + xv0.z * w2 + xv0.w * w3;
            acc1 += xv1.x * w0 + xv1.y * w1 + xv1.z * w2 + xv1.w * w3;
        }
        acc0 += b4; acc1 += b4;
        if (mat == 1) { acc0 *= kscale; acc1 *= kscale; }
        if (mat == 3) {
            acc0.x = 1.f/(1.f+__expf(-acc0.x)); acc0.y = 1.f/(1.f+__expf(-acc0.y));
            acc0.z = 1.f/(1.f+__expf(-acc0.z)); acc0.w = 1.f/(1.f+__expf(-acc0.w));
            acc1.x = 1.f/(1.f+__expf(-acc1.x)); acc1.y = 1.f/(1.f+__expf(-acc1.y));
            acc1.z = 1.f/(1.f+__expf(-acc1.z)); acc1.w = 1.f/(1.f+__expf(-acc1.w));
        }
        *(f4_t*)&DST[r0][c4]     = acc0;
        *(f4_t*)&DST[r0 + 1][c4] = acc1;
        __syncthreads();   // q,k,v,o of group visible (itf too, for g=0)

        // ---- c0q for this thread's 2 rows ----
        float c0q0 = 0.f, c0q1 = 0.f;
        {
            const float* c0row = c0 + (size_t)col * M_;
            #pragma unroll 2
            for (int j4 = 0; j4 < M_; j4 += 4) {
                f4_t w4 = *(const f4_t*)(c0row + j4);
                f4_t qa = *(const f4_t*)&qs[r0][j4];
                f4_t qb = *(const f4_t*)&qs[r0 + 1][j4];
                c0q0 = fmaf(w4.x, qa.x, fmaf(w4.y, qa.y, fmaf(w4.z, qa.z, fmaf(w4.w, qa.w, c0q0))));
                c0q1 = fmaf(w4.x, qb.x, fmaf(w4.y, qb.y, fmaf(w4.z, qb.z, fmaf(w4.w, qb.w, c0q1))));
            }
        }

        // ---- kq, n0q: one wave per row of the group ----
        {
            const int srow = g * GRP + (t >> 6);
            const int l    = t & 63;
            float ka = ks[srow][l],      kb = ks[srow][l + 64];
            float qa = qs[srow][l],      qb = qs[srow][l + 64];
            float na = n0[l],            nb = n0[l + 64];
            float pkq = fmaf(ka, qa, kb * qb);
            float pnq = fmaf(na, qa, nb * qb);
            #pragma unroll
            for (int m = 1; m < 64; m <<= 1) { pkq += __shfl_xor(pkq, m); pnq += __shfl_xor(pnq, m); }
            if (l == 0) { scal[srow][0] = pkq; scal[srow][1] = pnq; }
        }
        __syncthreads();   // scal visible

        // ---- h, n for this thread's 2 rows ----
        #pragma unroll
        for (int rr = 0; rr < 2; ++rr) {
            const int row = r0 + rr;
            const size_t grow = (size_t)(row0 + row);
            const float iv = itf[row][0], fv = itf[row][1];
            const float kv = ks[row][col];
            out_n[grow * M_ + col] = fmaf(fv, n0[col], iv * kv);
            const float nq    = fmaf(fv, scal[row][1], iv * scal[row][0]);
            const float denom = fmaxf(fabsf(nq), 1.0f);
            const float c0q   = rr ? c0q1 : c0q0;
            const float ht = fmaf(fv, c0q, iv * vs[row][col] * scal[row][0]) / denom;
            out_h[grow * H_ + col] = os_[row][col] * ht;
        }

        // ---- stream this group's 4 rows of c (fire-and-forget nt stores) ----
        {
            const int base = t * 4;
            const int j    = base & 127;
            #pragma unroll 2
            for (int ch = 0; ch < 16; ++ch) {
                const int p = (ch << 10) + base;
                const int m = p >> 7;
                f4_t c0v = *(const f4_t*)(c0 + p);
                #pragma unroll
                for (int r = 0; r < GRP; ++r) {
                    const int row = g * GRP + r;
                    f4_t k4 = *(const f4_t*)&ks[row][j];
                    float s = itf[row][0] * vs[row][m];
                    f4_t o4 = itf[row][1] * c0v + s * k4;
                    __builtin_nontemporal_store(o4,
                        (f4_t*)(out_c + (size_t)(row0 + row) * (M_ * M_) + p));
                }
            }
        }
        // no barrier here: next group's GEMM reads xs (stable) and writes
        // disjoint DST rows; its __syncthreads orders everything else.
    }
}

extern "C" void kernel_launch(void* const* d_in, const int* in_sizes, int n_in,
                              void* d_out, int out_size, void* d_ws, size_t ws_size,
                              hipStream_t stream) {
    const float* x   = (const float*)d_in[0];
    const float* c0  = (const float*)d_in[1];
    const float* n0  = (const float*)d_in[2];
    const float* w_q = (const float*)d_in[3];  const float* b_q = (const float*)d_in[4];
    const float* w_k = (const float*)d_in[5];  const float* b_k = (const float*)d_in[6];
    const float* w_v = (const float*)d_in[7];  const float* b_v = (const float*)d_in[8];
    const float* w_i = (const float*)d_in[9];  const float* b_i = (const float*)d_in[10];
    const float* w_f = (const float*)d_in[11]; const float* b_f = (const float*)d_in[12];
    const float* w_o = (const float*)d_in[13]; const float* b_o = (const float*)d_in[14];

    float* out   = (float*)d_out;
    float* out_h = out;
    float* out_c = out + (size_t)NROWS * H_;
    float* out_n = out_c + (size_t)NROWS * M_ * M_;

    hipLaunchKernelGGL(xlstm_fused, dim3(NROWS / RPB), dim3(TPB), 0, stream,
                       x, c0, n0, w_q, b_q, w_k, b_k, w_v, b_v,
                       w_i, b_i, w_f, b_f, w_o, b_o,
                       out_h, out_c, out_n);
}

// Round 12
// 138.285 us; speedup vs baseline: 1.1059x; 1.0680x over previous
//
#include <hip/hip_runtime.h>
#include <math.h>

#define B_    4
#define S_    2048
#define IN_   256
#define H_    128
#define M_    128
#define NROWS (B_ * S_)     // 8192
#define RPB   16            // rows per block
#define GRP   4             // rows per pipeline group
#define NGRP  4
#define TPB   512           // 8 waves: 0-3 producers, 4-7 consumers
#define XPAD  260

typedef float f4_t __attribute__((ext_vector_type(4)));

// Wave-specialized pipelined kernel. Per block (16 rows):
//   producers (t<256): proj GEMM per 4-row group -> LDS dbuf; c0q+scal; h,n.
//   consumers (t>=256): stream c for the PREVIOUS group from LDS (nt stores).
// vmcnt is per-wave, so consumer store drains never block producer weight
// loads; every block always has both phases live -> stores overlap compute.
__global__ __launch_bounds__(TPB) void xlstm_pipe(
    const float* __restrict__ x,
    const float* __restrict__ c0,
    const float* __restrict__ n0,
    const float* __restrict__ w_q, const float* __restrict__ b_q,
    const float* __restrict__ w_k, const float* __restrict__ b_k,
    const float* __restrict__ w_v, const float* __restrict__ b_v,
    const float* __restrict__ w_i, const float* __restrict__ b_i,
    const float* __restrict__ w_f, const float* __restrict__ b_f,
    const float* __restrict__ w_o, const float* __restrict__ b_o,
    float* __restrict__ out_h,
    float* __restrict__ out_c,
    float* __restrict__ out_n)
{
    __shared__ float xs[RPB][XPAD];        // 16.6 KB
    __shared__ float bq[2][GRP][M_];       // 4 KB each x 4 arrays = 16 KB
    __shared__ float bk[2][GRP][M_];
    __shared__ float bv[2][GRP][M_];
    __shared__ float bo[2][GRP][M_];
    __shared__ float itf[RPB][2];
    __shared__ float scalb[2][GRP][2];

    const int t    = threadIdx.x;
    const int row0 = blockIdx.x * RPB;
    const bool prod = (t < 256);

    // ---- stage x (all 512 threads) ----
    for (int p4 = t; p4 < RPB * IN_ / 4; p4 += TPB) {
        int p = p4 * 4;
        float4 v = *(const float4*)(x + (size_t)row0 * IN_ + p);
        *(float4*)&xs[p >> 8][p & 255] = v;
    }
    __syncthreads();

    // producer mapping: 4 cols x 1 matrix x 2 rows, full k
    const int cg  = t & 31;
    const int mat = (t >> 5) & 3;          // 0=q 1=k 2=v 3=o
    const int rh  = (t >> 7) & 1;
    const int c4  = cg * 4;
    const int col = t & 127;
    const float* W    = (mat==0)? w_q : (mat==1)? w_k : (mat==2)? w_v : w_o;
    const float* BIAS = (mat==0)? b_q : (mat==1)? b_k : (mat==2)? b_v : b_o;
    const f4_t bias4 = *(const f4_t*)(BIAS + c4);
    const float kscale = 0.08838834764831843f;   // 1/sqrt(128)

    // consumer mapping
    const int ct = t & 255;

    float c0qA = 0.f, c0qB = 0.f;          // carried group->next-stage

    #pragma unroll 1
    for (int s = 0; s <= NGRP; ++s) {
        // ================= sub-stage A =================
        if (prod) {
            if (s == 0) {
                // gates for all 16 rows (wave-parallel)
                const int gr = t >> 4, gseg = t & 15;
                const float* xrow = &xs[gr][gseg * 16];
                float pi = 0.f, pf = 0.f;
                #pragma unroll
                for (int u = 0; u < 4; ++u) {
                    float4 xv  = *(const float4*)(xrow + u * 4);
                    float4 wiv = *(const float4*)(w_i + gseg * 16 + u * 4);
                    float4 wfv = *(const float4*)(w_f + gseg * 16 + u * 4);
                    pi = fmaf(xv.x,wiv.x, fmaf(xv.y,wiv.y, fmaf(xv.z,wiv.z, fmaf(xv.w,wiv.w, pi))));
                    pf = fmaf(xv.x,wfv.x, fmaf(xv.y,wfv.y, fmaf(xv.z,wfv.z, fmaf(xv.w,wfv.w, pf))));
                }
                #pragma unroll
                for (int mm = 1; mm < 16; mm <<= 1) { pi += __shfl_xor(pi, mm); pf += __shfl_xor(pf, mm); }
                if (gseg == 0) {
                    itf[gr][0] = __expf(pi + b_i[0]);
                    itf[gr][1] = 1.f / (1.f + __expf(-(pf + b_f[0])));
                }
            }
            if (s > 0) {
                // h, n for group s-1 (uses scal/c0q from previous subB)
                const int b = (s - 1) & 1;
                #pragma unroll
                for (int rr = 0; rr < 2; ++rr) {
                    const int lrow = rh * 2 + rr;
                    const int row  = (s - 1) * GRP + lrow;
                    const size_t grow = (size_t)(row0 + row);
                    const float iv = itf[row][0], fv = itf[row][1];
                    out_n[grow * M_ + col] = fmaf(fv, n0[col], iv * bk[b][lrow][col]);
                    const float kq  = scalb[b][lrow][0];
                    const float n0q = scalb[b][lrow][1];
                    const float nq = fmaf(fv, n0q, iv * kq);
                    const float denom = fmaxf(fabsf(nq), 1.f);
                    const float c0q = rr ? c0qB : c0qA;
                    const float ht = fmaf(fv, c0q, iv * bv[b][lrow][col] * kq) / denom;
                    out_h[grow * H_ + col] = bo[b][lrow][col] * ht;
                }
            }
            if (s < NGRP) {
                // GEMM group s -> buf[s&1]
                const int b  = s & 1;
                const int r0 = s * GRP + rh * 2;
                f4_t acc0 = (f4_t){0.f,0.f,0.f,0.f};
                f4_t acc1 = (f4_t){0.f,0.f,0.f,0.f};
                #pragma unroll 4
                for (int it = 0; it < 64; ++it) {
                    const int k0 = it * 4;
                    const float* wp = W + (size_t)k0 * H_ + c4;
                    f4_t w0 = *(const f4_t*)(wp);
                    f4_t w1 = *(const f4_t*)(wp + H_);
                    f4_t w2 = *(const f4_t*)(wp + 2 * H_);
                    f4_t w3 = *(const f4_t*)(wp + 3 * H_);
                    f4_t xv0 = *(const f4_t*)&xs[r0][k0];
                    f4_t xv1 = *(const f4_t*)&xs[r0 + 1][k0];
                    acc0 += xv0.x*w0 + xv0.y*w1 + xv0.z*w2 + xv0.w*w3;
                    acc1 += xv1.x*w0 + xv1.y*w1 + xv1.z*w2 + xv1.w*w3;
                }
                acc0 += bias4; acc1 += bias4;
                if (mat == 1) { acc0 *= kscale; acc1 *= kscale; }
                if (mat == 3) {
                    acc0.x = 1.f/(1.f+__expf(-acc0.x)); acc0.y = 1.f/(1.f+__expf(-acc0.y));
                    acc0.z = 1.f/(1.f+__expf(-acc0.z)); acc0.w = 1.f/(1.f+__expf(-acc0.w));
                    acc1.x = 1.f/(1.f+__expf(-acc1.x)); acc1.y = 1.f/(1.f+__expf(-acc1.y));
                    acc1.z = 1.f/(1.f+__expf(-acc1.z)); acc1.w = 1.f/(1.f+__expf(-acc1.w));
                }
                float (*DST)[M_] = (mat==0)? bq[b] : (mat==1)? bk[b] : (mat==2)? bv[b] : bo[b];
                const int lr = rh * 2;
                *(f4_t*)&DST[lr][c4]     = acc0;
                *(f4_t*)&DST[lr + 1][c4] = acc1;
            }
        } else if (s > 0) {
            // consumers: stream local rows 0,1 of group s-1
            const int b     = (s - 1) & 1;
            const int gbase = (s - 1) * GRP;
            const int base  = ct * 4;
            const int j     = base & 127;
            #pragma unroll 2
            for (int ch = 0; ch < 16; ++ch) {
                const int p = (ch << 10) + base;
                const int m = p >> 7;
                f4_t c0v = *(const f4_t*)(c0 + p);
                #pragma unroll
                for (int r = 0; r < 2; ++r) {
                    const int row = gbase + r;
                    f4_t k4 = *(const f4_t*)&bk[b][r][j];
                    float sf = itf[row][0] * bv[b][r][m];
                    f4_t o4 = itf[row][1] * c0v + sf * k4;
                    __builtin_nontemporal_store(o4,
                        (f4_t*)(out_c + (size_t)(row0 + row) * (M_ * M_) + p));
                }
            }
        }
        __syncthreads();
        // ================= sub-stage B =================
        if (prod) {
            if (s < NGRP) {
                const int b  = s & 1;
                const int lr = rh * 2;
                // c0q for group s (into carried registers)
                float a0 = 0.f, a1 = 0.f;
                const float* c0row = c0 + (size_t)col * M_;
                #pragma unroll 2
                for (int j4 = 0; j4 < M_; j4 += 4) {
                    f4_t w4 = *(const f4_t*)(c0row + j4);
                    f4_t qa = *(const f4_t*)&bq[b][lr][j4];
                    f4_t qb = *(const f4_t*)&bq[b][lr + 1][j4];
                    a0 = fmaf(w4.x,qa.x, fmaf(w4.y,qa.y, fmaf(w4.z,qa.z, fmaf(w4.w,qa.w, a0))));
                    a1 = fmaf(w4.x,qb.x, fmaf(w4.y,qb.y, fmaf(w4.z,qb.z, fmaf(w4.w,qb.w, a1))));
                }
                c0qA = a0; c0qB = a1;
                // scal (kq, n0q): producer wave wv handles local row wv
                const int wv = t >> 6;     // 0..3
                const int l  = t & 63;
                const float ka  = bk[b][wv][l], kb2 = bk[b][wv][l + 64];
                const float qa2 = bq[b][wv][l], qb2 = bq[b][wv][l + 64];
                float pkq = fmaf(ka, qa2, kb2 * qb2);
                float pnq = fmaf(n0[l], qa2, n0[l + 64] * qb2);
                #pragma unroll
                for (int mm = 1; mm < 64; mm <<= 1) { pkq += __shfl_xor(pkq, mm); pnq += __shfl_xor(pnq, mm); }
                if (l == 0) { scalb[b][wv][0] = pkq; scalb[b][wv][1] = pnq; }
            }
        } else if (s > 0) {
            // consumers: stream local rows 2,3 of group s-1
            const int b     = (s - 1) & 1;
            const int gbase = (s - 1) * GRP;
            const int base  = ct * 4;
            const int j     = base & 127;
            #pragma unroll 2
            for (int ch = 0; ch < 16; ++ch) {
                const int p = (ch << 10) + base;
                const int m = p >> 7;
                f4_t c0v = *(const f4_t*)(c0 + p);
                #pragma unroll
                for (int r = 2; r < 4; ++r) {
                    const int row = gbase + r;
                    f4_t k4 = *(const f4_t*)&bk[b][r][j];
                    float sf = itf[row][0] * bv[b][r][m];
                    f4_t o4 = itf[row][1] * c0v + sf * k4;
                    __builtin_nontemporal_store(o4,
                        (f4_t*)(out_c + (size_t)(row0 + row) * (M_ * M_) + p));
                }
            }
        }
        __syncthreads();
    }
}

extern "C" void kernel_launch(void* const* d_in, const int* in_sizes, int n_in,
                              void* d_out, int out_size, void* d_ws, size_t ws_size,
                              hipStream_t stream) {
    const float* x   = (const float*)d_in[0];
    const float* c0  = (const float*)d_in[1];
    const float* n0  = (const float*)d_in[2];
    const float* w_q = (const float*)d_in[3];  const float* b_q = (const float*)d_in[4];
    const float* w_k = (const float*)d_in[5];  const float* b_k = (const float*)d_in[6];
    const float* w_v = (const float*)d_in[7];  const float* b_v = (const float*)d_in[8];
    const float* w_i = (const float*)d_in[9];  const float* b_i = (const float*)d_in[10];
    const float* w_f = (const float*)d_in[11]; const float* b_f = (const float*)d_in[12];
    const float* w_o = (const float*)d_in[13]; const float* b_o = (const float*)d_in[14];

    float* out   = (float*)d_out;
    float* out_h = out;
    float* out_c = out + (size_t)NROWS * H_;
    float* out_n = out_c + (size_t)NROWS * M_ * M_;

    hipLaunchKernelGGL(xlstm_pipe, dim3(NROWS / RPB), dim3(TPB), 0, stream,
                       x, c0, n0, w_q, b_q, w_k, b_k, w_v, b_v,
                       w_i, b_i, w_f, b_f, w_o, b_o,
                       out_h, out_c, out_n);
}